// Round 1
// baseline (281.185 us; speedup 1.0000x reference)
//
#include <hip/hip_runtime.h>
#include <cmath>

#define R_ROWS 1000
#define NCLS   81
#define REGW   (NCLS * 4)
#define SCORE_T 0.05f
#define NMS_T   0.5f
#define NEG_S  -1e9f
#define DETS   100
#define CLIP_V 4.135166556742356f   // log(1000/16), rounded to nearest f32 by compiler
#define MAXC   1000

// ---------- exact-order helpers (no FMA contraction: match numpy/XLA separate rounding) ----------

__device__ __forceinline__ float4 decode_clip(const float* __restrict__ prop,
                                              const float* __restrict__ reg,
                                              int r, int ccol, float wmax, float hmax) {
    float x1 = prop[r * 4 + 0], y1 = prop[r * 4 + 1];
    float x2 = prop[r * 4 + 2], y2 = prop[r * 4 + 3];
    float w  = __fadd_rn(__fsub_rn(x2, x1), 1.0f);
    float h  = __fadd_rn(__fsub_rn(y2, y1), 1.0f);
    float cx = __fadd_rn(x1, __fmul_rn(0.5f, w));
    float cy = __fadd_rn(y1, __fmul_rn(0.5f, h));
    const float* rr = reg + r * REGW + 4 * ccol;
    float dx = rr[0] / 10.0f;
    float dy = rr[1] / 10.0f;
    float dw = fminf(rr[2] / 5.0f, CLIP_V);
    float dh = fminf(rr[3] / 5.0f, CLIP_V);
    float pcx = __fadd_rn(__fmul_rn(dx, w), cx);
    float pcy = __fadd_rn(__fmul_rn(dy, h), cy);
    float pw  = __fmul_rn(expf(dw), w);
    float ph  = __fmul_rn(expf(dh), h);
    float ox1 = __fsub_rn(pcx, __fmul_rn(0.5f, pw));
    float oy1 = __fsub_rn(pcy, __fmul_rn(0.5f, ph));
    float ox2 = __fsub_rn(__fadd_rn(pcx, __fmul_rn(0.5f, pw)), 1.0f);
    float oy2 = __fsub_rn(__fadd_rn(pcy, __fmul_rn(0.5f, ph)), 1.0f);
    float4 o;
    o.x = fminf(fmaxf(ox1, 0.0f), wmax);
    o.y = fminf(fmaxf(oy1, 0.0f), hmax);
    o.z = fminf(fmaxf(ox2, 0.0f), wmax);
    o.w = fminf(fmaxf(oy2, 0.0f), hmax);
    return o;
}

__device__ __forceinline__ float iou_legacy(float ax1, float ay1, float ax2, float ay2,
                                            float bx1, float by1, float bx2, float by2) {
    float aw = __fadd_rn(__fsub_rn(ax2, ax1), 1.0f);
    float ah = __fadd_rn(__fsub_rn(ay2, ay1), 1.0f);
    float areaA = __fmul_rn(aw, ah);
    float bw = __fadd_rn(__fsub_rn(bx2, bx1), 1.0f);
    float bh = __fadd_rn(__fsub_rn(by2, by1), 1.0f);
    float areaB = __fmul_rn(bw, bh);
    float ltx = fmaxf(ax1, bx1), lty = fmaxf(ay1, by1);
    float rbx = fminf(ax2, bx2), rby = fminf(ay2, by2);
    float wx = fmaxf(__fadd_rn(__fsub_rn(rbx, ltx), 1.0f), 0.0f);
    float wy = fmaxf(__fadd_rn(__fsub_rn(rby, lty), 1.0f), 0.0f);
    float inter = __fmul_rn(wx, wy);
    float denom = __fsub_rn(__fadd_rn(areaA, areaB), inter);
    return inter / denom;
}

// ---------- Kernel A: per-row softmax stats (max, sum of exp) ----------

__global__ __launch_bounds__(64) void k_softmax_stats(const float* __restrict__ logits,
                                                      float* __restrict__ rowmax,
                                                      float* __restrict__ rowsum,
                                                      int* __restrict__ gcount) {
    int r = blockIdx.x;
    int l = threadIdx.x;
    if (r == 0 && l == 0) *gcount = 0;   // kernel B runs after A on the same stream
    float v1 = logits[r * NCLS + l];
    float v2 = (l < NCLS - 64) ? logits[r * NCLS + 64 + l] : -INFINITY;
    float m = fmaxf(v1, v2);
    #pragma unroll
    for (int off = 32; off; off >>= 1) m = fmaxf(m, __shfl_xor(m, off));
    float s = expf(__fsub_rn(v1, m));
    if (l < NCLS - 64) s = __fadd_rn(s, expf(__fsub_rn(v2, m)));
    #pragma unroll
    for (int off = 32; off; off >>= 1) s = __fadd_rn(s, __shfl_xor(s, off));
    if (l == 0) { rowmax[r] = m; rowsum[r] = s; }
}

// ---------- Kernel B: one workgroup per class — gather valid, sort, NMS, append kept ----------

__global__ __launch_bounds__(256) void k_nms_class(const float* __restrict__ logits,
                                                   const float* __restrict__ reg,
                                                   const float* __restrict__ prop,
                                                   const float* __restrict__ rowmax,
                                                   const float* __restrict__ rowsum,
                                                   const int* __restrict__ piw,
                                                   const int* __restrict__ pih,
                                                   float* __restrict__ kscores,
                                                   int* __restrict__ kflats,
                                                   int* __restrict__ gcount,
                                                   int cap) {
    __shared__ float us[MAXC];    __shared__ int uidx[MAXC];
    __shared__ float ss[MAXC];    __shared__ int sidx[MAXC];
    __shared__ float bx[MAXC][4];
    __shared__ int   supp[MAXC];
    __shared__ int   cnt;

    const int cidx = blockIdx.x;       // 0..79
    const int ccol = cidx + 1;         // skip background class 0
    const int t = threadIdx.x;

    if (t == 0) cnt = 0;
    __syncthreads();

    // 1) valid candidates (score > thresh), unsorted compaction into LDS
    for (int r = t; r < R_ROWS; r += blockDim.x) {
        float z = logits[r * NCLS + ccol];
        float s = expf(__fsub_rn(z, rowmax[r])) / rowsum[r];
        if (s > SCORE_T) {
            int p = atomicAdd(&cnt, 1);
            us[p] = s; uidx[p] = r;
        }
    }
    __syncthreads();
    const int M = cnt;

    // 2) exact rank sort: (score desc, row asc) — matches stable argsort(-masked)
    for (int i = t; i < M; i += blockDim.x) {
        float si = us[i]; int ri = uidx[i];
        int rank = 0;
        for (int j = 0; j < M; j++) {
            float sj = us[j]; int rj = uidx[j];
            rank += (sj > si) || (sj == si && rj < ri);
        }
        ss[rank] = si; sidx[rank] = ri;
    }
    __syncthreads();

    // 3) decode + clip boxes for sorted candidates
    const float wmax = (float)(*piw - 1);
    const float hmax = (float)(*pih - 1);
    for (int i = t; i < M; i += blockDim.x) {
        float4 b = decode_clip(prop, reg, sidx[i], ccol, wmax, hmax);
        bx[i][0] = b.x; bx[i][1] = b.y; bx[i][2] = b.z; bx[i][3] = b.w;
        supp[i] = 0;
    }
    __syncthreads();

    // 4) greedy NMS: sequential over i, parallel suppression of j > i
    for (int i = 0; i < M; i++) {
        if (!supp[i]) {
            float ax1 = bx[i][0], ay1 = bx[i][1], ax2 = bx[i][2], ay2 = bx[i][3];
            for (int j = i + 1 + t; j < M; j += blockDim.x) {
                if (!supp[j]) {
                    float v = iou_legacy(ax1, ay1, ax2, ay2,
                                         bx[j][0], bx[j][1], bx[j][2], bx[j][3]);
                    if (v > NMS_T) supp[j] = 1;
                }
            }
        }
        __syncthreads();
    }

    // 5) append kept candidates to global list (order irrelevant; kernel C sorts)
    for (int i = t; i < M; i += blockDim.x) {
        if (!supp[i]) {
            int p = atomicAdd(gcount, 1);
            if (p < cap) {
                kscores[p] = ss[i];
                kflats[p]  = cidx * R_ROWS + sidx[i];
            }
        }
    }
}

// ---------- Kernel C: exact top-100 by (score desc, flat asc), decode, write outputs ----------

__global__ __launch_bounds__(256) void k_topk(const float* __restrict__ reg,
                                              const float* __restrict__ prop,
                                              float* __restrict__ kscores,
                                              int* __restrict__ kflats,
                                              const int* __restrict__ gcount,
                                              int cap,
                                              const int* __restrict__ piw,
                                              const int* __restrict__ pih,
                                              float* __restrict__ out) {
    __shared__ float rs[256]; __shared__ int rf[256]; __shared__ int rp[256];
    __shared__ float sel_s[DETS]; __shared__ int sel_f[DETS];

    const int t = threadIdx.x;
    int K = *gcount; if (K > cap) K = cap;
    const int nsel = (K < DETS) ? K : DETS;

    for (int n = 0; n < nsel; n++) {
        float bestS = -3e38f; int bestF = 0x7fffffff; int bestP = -1;
        for (int p = t; p < K; p += 256) {
            float s = kscores[p]; int f = kflats[p];
            if (s > bestS || (s == bestS && f < bestF)) { bestS = s; bestF = f; bestP = p; }
        }
        rs[t] = bestS; rf[t] = bestF; rp[t] = bestP;
        __syncthreads();
        for (int off = 128; off; off >>= 1) {
            if (t < off) {
                if (rs[t + off] > rs[t] || (rs[t + off] == rs[t] && rf[t + off] < rf[t])) {
                    rs[t] = rs[t + off]; rf[t] = rf[t + off]; rp[t] = rp[t + off];
                }
            }
            __syncthreads();
        }
        if (t == 0) {
            sel_s[n] = rs[0]; sel_f[n] = rf[0];
            kscores[rp[0]] = -3e38f;   // remove winner from further selection
        }
        __syncthreads();
    }

    // fill tail with NEG entries: smallest flat indices NOT in kept set (top_k tie-break)
    if (t == 0 && nsel < DETS) {
        int n = nsel, f = 0;
        while (n < DETS) {
            bool used = false;
            for (int q = 0; q < K; q++) if (kflats[q] == f) { used = true; break; }
            if (!used) { sel_s[n] = NEG_S; sel_f[n] = f; n++; }
            f++;
        }
    }
    __syncthreads();

    const float wmax = (float)(*piw - 1);
    const float hmax = (float)(*pih - 1);
    if (t < DETS) {
        int f = sel_f[t];
        int cidx = f / R_ROWS;
        int r    = f % R_ROWS;
        float4 b = decode_clip(prop, reg, r, cidx + 1, wmax, hmax);
        out[t] = sel_s[t];
        out[DETS + 4 * t + 0] = b.x;
        out[DETS + 4 * t + 1] = b.y;
        out[DETS + 4 * t + 2] = b.z;
        out[DETS + 4 * t + 3] = b.w;
        out[DETS * 5 + t] = (float)(cidx + 1);
    }
}

// ---------- host launcher ----------

extern "C" void kernel_launch(void* const* d_in, const int* in_sizes, int n_in,
                              void* d_out, int out_size, void* d_ws, size_t ws_size,
                              hipStream_t stream) {
    (void)in_sizes; (void)n_in; (void)out_size;
    const float* logits = (const float*)d_in[0];
    const float* reg    = (const float*)d_in[1];
    const float* prop   = (const float*)d_in[2];
    const int*   piw    = (const int*)d_in[3];
    const int*   pih    = (const int*)d_in[4];
    float* out = (float*)d_out;

    // workspace layout (bytes): rowmax @0, rowsum @4096, gcount @8192, list @8256
    char* ws = (char*)d_ws;
    float* rowmax  = (float*)(ws);
    float* rowsum  = (float*)(ws + 4096);
    int*   gcount  = (int*)(ws + 8192);
    char*  listbuf = ws + 8256;

    // capacity for kept-candidate list (score f32 + flat i32 = 8B per entry)
    long avail = (long)ws_size - 8256;
    int cap = 80000;
    if (avail < (long)cap * 8) cap = (int)(avail / 8);
    if (cap < 1) cap = 1;
    float* kscores = (float*)listbuf;
    int*   kflats  = (int*)(listbuf + (size_t)cap * 4);

    k_softmax_stats<<<dim3(R_ROWS), dim3(64), 0, stream>>>(logits, rowmax, rowsum, gcount);
    k_nms_class<<<dim3(NCLS - 1), dim3(256), 0, stream>>>(logits, reg, prop, rowmax, rowsum,
                                                          piw, pih, kscores, kflats, gcount, cap);
    k_topk<<<dim3(1), dim3(256), 0, stream>>>(reg, prop, kscores, kflats, gcount, cap,
                                              piw, pih, out);
}

// Round 2
// 71.608 us; speedup vs baseline: 3.9267x; 3.9267x over previous
//
#include <hip/hip_runtime.h>
#include <cmath>

#define R_ROWS 1000
#define NCLS   81
#define REGW   (NCLS * 4)
#define SCORE_T 0.05f
#define NMS_T   0.5f
#define NEG_S  -1e9f
#define DETS   100
#define CLIP_V 4.135166556742356f   // log(1000/16)
#define MAXC   1000

#define RANK_BLOCKS 32
#define RANK_TILE   2048
#define MAXOWN      4              // covers K <= 32*256*4 = 32768 (max possible kept ~19000)
#define CAP_DEFAULT 20000

// ---------- exact-order helpers (no FMA contraction: match numpy/XLA separate rounding) ----------

__device__ __forceinline__ float4 decode_clip(const float* __restrict__ prop,
                                              const float* __restrict__ reg,
                                              int r, int ccol, float wmax, float hmax) {
    float x1 = prop[r * 4 + 0], y1 = prop[r * 4 + 1];
    float x2 = prop[r * 4 + 2], y2 = prop[r * 4 + 3];
    float w  = __fadd_rn(__fsub_rn(x2, x1), 1.0f);
    float h  = __fadd_rn(__fsub_rn(y2, y1), 1.0f);
    float cx = __fadd_rn(x1, __fmul_rn(0.5f, w));
    float cy = __fadd_rn(y1, __fmul_rn(0.5f, h));
    const float* rr = reg + r * REGW + 4 * ccol;
    float dx = rr[0] / 10.0f;
    float dy = rr[1] / 10.0f;
    float dw = fminf(rr[2] / 5.0f, CLIP_V);
    float dh = fminf(rr[3] / 5.0f, CLIP_V);
    float pcx = __fadd_rn(__fmul_rn(dx, w), cx);
    float pcy = __fadd_rn(__fmul_rn(dy, h), cy);
    float pw  = __fmul_rn(expf(dw), w);
    float ph  = __fmul_rn(expf(dh), h);
    float ox1 = __fsub_rn(pcx, __fmul_rn(0.5f, pw));
    float oy1 = __fsub_rn(pcy, __fmul_rn(0.5f, ph));
    float ox2 = __fsub_rn(__fadd_rn(pcx, __fmul_rn(0.5f, pw)), 1.0f);
    float oy2 = __fsub_rn(__fadd_rn(pcy, __fmul_rn(0.5f, ph)), 1.0f);
    float4 o;
    o.x = fminf(fmaxf(ox1, 0.0f), wmax);
    o.y = fminf(fmaxf(oy1, 0.0f), hmax);
    o.z = fminf(fmaxf(ox2, 0.0f), wmax);
    o.w = fminf(fmaxf(oy2, 0.0f), hmax);
    return o;
}

__device__ __forceinline__ float iou_legacy(float ax1, float ay1, float ax2, float ay2,
                                            float bx1, float by1, float bx2, float by2) {
    float aw = __fadd_rn(__fsub_rn(ax2, ax1), 1.0f);
    float ah = __fadd_rn(__fsub_rn(ay2, ay1), 1.0f);
    float areaA = __fmul_rn(aw, ah);
    float bw = __fadd_rn(__fsub_rn(bx2, bx1), 1.0f);
    float bh = __fadd_rn(__fsub_rn(by2, by1), 1.0f);
    float areaB = __fmul_rn(bw, bh);
    float ltx = fmaxf(ax1, bx1), lty = fmaxf(ay1, by1);
    float rbx = fminf(ax2, bx2), rby = fminf(ay2, by2);
    float wx = fmaxf(__fadd_rn(__fsub_rn(rbx, ltx), 1.0f), 0.0f);
    float wy = fmaxf(__fadd_rn(__fsub_rn(rby, lty), 1.0f), 0.0f);
    float inter = __fmul_rn(wx, wy);
    float denom = __fsub_rn(__fadd_rn(areaA, areaB), inter);
    return inter / denom;
}

// ---------- Kernel A: per-row softmax stats (max, sum of exp) ----------

__global__ __launch_bounds__(64) void k_softmax_stats(const float* __restrict__ logits,
                                                      float* __restrict__ rowmax,
                                                      float* __restrict__ rowsum,
                                                      int* __restrict__ gcount) {
    int r = blockIdx.x;
    int l = threadIdx.x;
    if (r == 0 && l == 0) *gcount = 0;   // kernel B runs after A on the same stream
    float v1 = logits[r * NCLS + l];
    float v2 = (l < NCLS - 64) ? logits[r * NCLS + 64 + l] : -INFINITY;
    float m = fmaxf(v1, v2);
    #pragma unroll
    for (int off = 32; off; off >>= 1) m = fmaxf(m, __shfl_xor(m, off));
    float s = expf(__fsub_rn(v1, m));
    if (l < NCLS - 64) s = __fadd_rn(s, expf(__fsub_rn(v2, m)));
    #pragma unroll
    for (int off = 32; off; off >>= 1) s = __fadd_rn(s, __shfl_xor(s, off));
    if (l == 0) { rowmax[r] = m; rowsum[r] = s; }
}

// ---------- Kernel B: one workgroup per class — gather valid, sort, NMS, append kept ----------

__global__ __launch_bounds__(256) void k_nms_class(const float* __restrict__ logits,
                                                   const float* __restrict__ reg,
                                                   const float* __restrict__ prop,
                                                   const float* __restrict__ rowmax,
                                                   const float* __restrict__ rowsum,
                                                   const int* __restrict__ piw,
                                                   const int* __restrict__ pih,
                                                   float* __restrict__ kscores,
                                                   int* __restrict__ kflats,
                                                   int* __restrict__ gcount,
                                                   int cap) {
    __shared__ float us[MAXC];    __shared__ int uidx[MAXC];
    __shared__ float ss[MAXC];    __shared__ int sidx[MAXC];
    __shared__ float bx[MAXC][4];
    __shared__ int   supp[MAXC];
    __shared__ int   cnt;

    const int cidx = blockIdx.x;       // 0..79
    const int ccol = cidx + 1;         // skip background class 0
    const int t = threadIdx.x;

    if (t == 0) cnt = 0;
    __syncthreads();

    // 1) valid candidates (score > thresh), unsorted compaction into LDS
    for (int r = t; r < R_ROWS; r += blockDim.x) {
        float z = logits[r * NCLS + ccol];
        float s = expf(__fsub_rn(z, rowmax[r])) / rowsum[r];
        if (s > SCORE_T) {
            int p = atomicAdd(&cnt, 1);
            us[p] = s; uidx[p] = r;
        }
    }
    __syncthreads();
    const int M = cnt;

    // 2) exact rank sort: (score desc, row asc) — matches stable argsort(-masked)
    for (int i = t; i < M; i += blockDim.x) {
        float si = us[i]; int ri = uidx[i];
        int rank = 0;
        for (int j = 0; j < M; j++) {
            float sj = us[j]; int rj = uidx[j];
            rank += (sj > si) || (sj == si && rj < ri);
        }
        ss[rank] = si; sidx[rank] = ri;
    }
    __syncthreads();

    // 3) decode + clip boxes for sorted candidates
    const float wmax = (float)(*piw - 1);
    const float hmax = (float)(*pih - 1);
    for (int i = t; i < M; i += blockDim.x) {
        float4 b = decode_clip(prop, reg, sidx[i], ccol, wmax, hmax);
        bx[i][0] = b.x; bx[i][1] = b.y; bx[i][2] = b.z; bx[i][3] = b.w;
        supp[i] = 0;
    }
    __syncthreads();

    // 4) greedy NMS: sequential over i, parallel suppression of j > i
    for (int i = 0; i < M; i++) {
        if (!supp[i]) {
            float ax1 = bx[i][0], ay1 = bx[i][1], ax2 = bx[i][2], ay2 = bx[i][3];
            for (int j = i + 1 + t; j < M; j += blockDim.x) {
                if (!supp[j]) {
                    float v = iou_legacy(ax1, ay1, ax2, ay2,
                                         bx[j][0], bx[j][1], bx[j][2], bx[j][3]);
                    if (v > NMS_T) supp[j] = 1;
                }
            }
        }
        __syncthreads();
    }

    // 5) append kept candidates to global list (order irrelevant; kernel C ranks)
    for (int i = t; i < M; i += blockDim.x) {
        if (!supp[i]) {
            int p = atomicAdd(gcount, 1);
            if (p < cap) {
                kscores[p] = ss[i];
                kflats[p]  = cidx * R_ROWS + sidx[i];
            }
        }
    }
}

// ---------- Kernel C1: parallel rank selection ----------
// key = (score_bits << 32) | ~flat : u64 compare == (score desc, flat asc) tie-break,
// exact for positive scores (IEEE positive floats are bit-monotone). Rank of entry i
// = #{j : key_j > key_i}; ranks are a bijection 0..K-1, rank<100 scatters to slot.

__global__ __launch_bounds__(256) void k_rank(const float* __restrict__ kscores,
                                              const int* __restrict__ kflats,
                                              const int* __restrict__ gcount,
                                              int cap,
                                              float* __restrict__ sel_s,
                                              int* __restrict__ sel_f) {
    __shared__ unsigned long long keys[RANK_TILE];
    int K = *gcount; if (K > cap) K = cap;
    const int t = threadIdx.x;
    const int gstride = RANK_BLOCKS * 256;
    const int base = blockIdx.x * 256 + t;

    unsigned long long myk[MAXOWN];
    int myr[MAXOWN];
    int nown = 0;
    for (int i = base; i < K && nown < MAXOWN; i += gstride) {
        float s = kscores[i];
        unsigned f = (unsigned)kflats[i];
        myk[nown] = ((unsigned long long)__float_as_uint(s) << 32) | (unsigned long long)(~f);
        myr[nown] = 0;
        nown++;
    }

    for (int j0 = 0; j0 < K; j0 += RANK_TILE) {
        int jn = K - j0; if (jn > RANK_TILE) jn = RANK_TILE;
        __syncthreads();
        for (int j = t; j < jn; j += 256) {
            float s = kscores[j0 + j];
            unsigned f = (unsigned)kflats[j0 + j];
            keys[j] = ((unsigned long long)__float_as_uint(s) << 32) | (unsigned long long)(~f);
        }
        __syncthreads();
        for (int o = 0; o < nown; o++) {
            unsigned long long ki = myk[o];
            int r = myr[o];
            #pragma unroll 4
            for (int j = 0; j < jn; j++) r += (keys[j] > ki);
            myr[o] = r;
        }
    }

    for (int o = 0; o < nown; o++) {
        if (myr[o] < DETS) {
            unsigned long long k = myk[o];
            sel_s[myr[o]] = __uint_as_float((unsigned)(k >> 32));
            sel_f[myr[o]] = (int)(~(unsigned)k);
        }
    }
}

// ---------- Kernel C2: tail-fill + decode + write 600 outputs ----------

__global__ __launch_bounds__(256) void k_finalize(const float* __restrict__ reg,
                                                  const float* __restrict__ prop,
                                                  const int* __restrict__ kflats,
                                                  const int* __restrict__ gcount,
                                                  int cap,
                                                  const int* __restrict__ piw,
                                                  const int* __restrict__ pih,
                                                  const float* __restrict__ sel_s_g,
                                                  const int* __restrict__ sel_f_g,
                                                  float* __restrict__ out) {
    __shared__ float sel_s[DETS]; __shared__ int sel_f[DETS];
    const int t = threadIdx.x;
    int K = *gcount; if (K > cap) K = cap;
    const int nsel = (K < DETS) ? K : DETS;

    if (t < nsel) { sel_s[t] = sel_s_g[t]; sel_f[t] = sel_f_g[t]; }
    __syncthreads();

    // fill tail with NEG entries: smallest flat indices NOT in kept set (top_k tie-break)
    if (t == 0 && nsel < DETS) {
        int n = nsel, f = 0;
        while (n < DETS) {
            bool used = false;
            for (int q = 0; q < K; q++) if (kflats[q] == f) { used = true; break; }
            if (!used) { sel_s[n] = NEG_S; sel_f[n] = f; n++; }
            f++;
        }
    }
    __syncthreads();

    const float wmax = (float)(*piw - 1);
    const float hmax = (float)(*pih - 1);
    if (t < DETS) {
        int f = sel_f[t];
        int cidx = f / R_ROWS;
        int r    = f % R_ROWS;
        float4 b = decode_clip(prop, reg, r, cidx + 1, wmax, hmax);
        out[t] = sel_s[t];
        out[DETS + 4 * t + 0] = b.x;
        out[DETS + 4 * t + 1] = b.y;
        out[DETS + 4 * t + 2] = b.z;
        out[DETS + 4 * t + 3] = b.w;
        out[DETS * 5 + t] = (float)(cidx + 1);
    }
}

// ---------- host launcher ----------

extern "C" void kernel_launch(void* const* d_in, const int* in_sizes, int n_in,
                              void* d_out, int out_size, void* d_ws, size_t ws_size,
                              hipStream_t stream) {
    (void)in_sizes; (void)n_in; (void)out_size;
    const float* logits = (const float*)d_in[0];
    const float* reg    = (const float*)d_in[1];
    const float* prop   = (const float*)d_in[2];
    const int*   piw    = (const int*)d_in[3];
    const int*   pih    = (const int*)d_in[4];
    float* out = (float*)d_out;

    // workspace layout (bytes):
    //   0     rowmax[1000]
    //   4096  rowsum[1000]
    //   8192  gcount
    //   8256  sel_s[100]
    //   8768  sel_f[100]
    //   9280  kscores[cap] ; kflats[cap]
    char* ws = (char*)d_ws;
    float* rowmax  = (float*)(ws);
    float* rowsum  = (float*)(ws + 4096);
    int*   gcount  = (int*)(ws + 8192);
    float* sel_s   = (float*)(ws + 8256);
    int*   sel_f   = (int*)(ws + 8768);
    char*  listbuf = ws + 9280;

    long avail = (long)ws_size - 9280;
    int cap = CAP_DEFAULT;                     // max possible kept: <=19/row * 1000 = 19000
    if (avail < (long)cap * 8) cap = (int)(avail / 8);
    if (cap < 1) cap = 1;
    float* kscores = (float*)listbuf;
    int*   kflats  = (int*)(listbuf + (size_t)cap * 4);

    k_softmax_stats<<<dim3(R_ROWS), dim3(64), 0, stream>>>(logits, rowmax, rowsum, gcount);
    k_nms_class<<<dim3(NCLS - 1), dim3(256), 0, stream>>>(logits, reg, prop, rowmax, rowsum,
                                                          piw, pih, kscores, kflats, gcount, cap);
    k_rank<<<dim3(RANK_BLOCKS), dim3(256), 0, stream>>>(kscores, kflats, gcount, cap, sel_s, sel_f);
    k_finalize<<<dim3(1), dim3(256), 0, stream>>>(reg, prop, kflats, gcount, cap,
                                                  piw, pih, sel_s, sel_f, out);
}

// Round 3
// 44.811 us; speedup vs baseline: 6.2749x; 1.5980x over previous
//
#include <hip/hip_runtime.h>
#include <cmath>

#define R_ROWS 1000
#define NCLS   81
#define REGW   (NCLS * 4)
#define SCORE_T 0.05f
#define NMS_T   0.5f
#define NEG_S  -1e9f
#define DETS   100
#define CLIP_V 4.135166556742356f   // log(1000/16)
#define MAXC   1000

#define NBINS   1024
#define SEL_CAP 2048
#define CAP_DEFAULT 20000           // max possible kept: <=19 classes/row (sum p = 1) * 1000 rows

// ---------- exact-order helpers (no FMA contraction: match numpy/XLA separate rounding) ----------

__device__ __forceinline__ float4 decode_clip(const float* __restrict__ prop,
                                              const float* __restrict__ reg,
                                              int r, int ccol, float wmax, float hmax) {
    float x1 = prop[r * 4 + 0], y1 = prop[r * 4 + 1];
    float x2 = prop[r * 4 + 2], y2 = prop[r * 4 + 3];
    float w  = __fadd_rn(__fsub_rn(x2, x1), 1.0f);
    float h  = __fadd_rn(__fsub_rn(y2, y1), 1.0f);
    float cx = __fadd_rn(x1, __fmul_rn(0.5f, w));
    float cy = __fadd_rn(y1, __fmul_rn(0.5f, h));
    const float* rr = reg + r * REGW + 4 * ccol;
    float dx = rr[0] / 10.0f;
    float dy = rr[1] / 10.0f;
    float dw = fminf(rr[2] / 5.0f, CLIP_V);
    float dh = fminf(rr[3] / 5.0f, CLIP_V);
    float pcx = __fadd_rn(__fmul_rn(dx, w), cx);
    float pcy = __fadd_rn(__fmul_rn(dy, h), cy);
    float pw  = __fmul_rn(expf(dw), w);
    float ph  = __fmul_rn(expf(dh), h);
    float ox1 = __fsub_rn(pcx, __fmul_rn(0.5f, pw));
    float oy1 = __fsub_rn(pcy, __fmul_rn(0.5f, ph));
    float ox2 = __fsub_rn(__fadd_rn(pcx, __fmul_rn(0.5f, pw)), 1.0f);
    float oy2 = __fsub_rn(__fadd_rn(pcy, __fmul_rn(0.5f, ph)), 1.0f);
    float4 o;
    o.x = fminf(fmaxf(ox1, 0.0f), wmax);
    o.y = fminf(fmaxf(oy1, 0.0f), hmax);
    o.z = fminf(fmaxf(ox2, 0.0f), wmax);
    o.w = fminf(fmaxf(oy2, 0.0f), hmax);
    return o;
}

__device__ __forceinline__ float iou_legacy(float ax1, float ay1, float ax2, float ay2,
                                            float bx1, float by1, float bx2, float by2) {
    float aw = __fadd_rn(__fsub_rn(ax2, ax1), 1.0f);
    float ah = __fadd_rn(__fsub_rn(ay2, ay1), 1.0f);
    float areaA = __fmul_rn(aw, ah);
    float bw = __fadd_rn(__fsub_rn(bx2, bx1), 1.0f);
    float bh = __fadd_rn(__fsub_rn(by2, by1), 1.0f);
    float areaB = __fmul_rn(bw, bh);
    float ltx = fmaxf(ax1, bx1), lty = fmaxf(ay1, by1);
    float rbx = fminf(ax2, bx2), rby = fminf(ay2, by2);
    float wx = fmaxf(__fadd_rn(__fsub_rn(rbx, ltx), 1.0f), 0.0f);
    float wy = fmaxf(__fadd_rn(__fsub_rn(rby, lty), 1.0f), 0.0f);
    float inter = __fmul_rn(wx, wy);
    float denom = __fsub_rn(__fadd_rn(areaA, areaB), inter);
    return inter / denom;
}

// monotone coarse bin of a positive float score (positive IEEE bits are order-preserving)
__device__ __forceinline__ int bin_of(float s) {
    int idx = (int)(__float_as_uint(s) >> 16) - 0x3D00;   // scores in (0.05,1] -> [76,640]
    return idx < 0 ? 0 : (idx > NBINS - 1 ? NBINS - 1 : idx);
}

__device__ __forceinline__ unsigned long long key_of(float s, unsigned f) {
    // (score desc, flat asc) as one monotone u64
    return ((unsigned long long)__float_as_uint(s) << 32) | (unsigned long long)(~f);
}

// ---------- Kernel A: per-row softmax stats + zero hist/gcount ----------

__global__ __launch_bounds__(64) void k_softmax_stats(const float* __restrict__ logits,
                                                      float* __restrict__ rowmax,
                                                      float* __restrict__ rowsum,
                                                      int* __restrict__ gcount,
                                                      int* __restrict__ hist) {
    int r = blockIdx.x;
    int l = threadIdx.x;
    if (r < NBINS / 64) hist[r * 64 + l] = 0;
    if (r == 0 && l == 0) *gcount = 0;
    float v1 = logits[r * NCLS + l];
    float v2 = (l < NCLS - 64) ? logits[r * NCLS + 64 + l] : -INFINITY;
    float m = fmaxf(v1, v2);
    #pragma unroll
    for (int off = 32; off; off >>= 1) m = fmaxf(m, __shfl_xor(m, off));
    float s = expf(__fsub_rn(v1, m));
    if (l < NCLS - 64) s = __fadd_rn(s, expf(__fsub_rn(v2, m)));
    #pragma unroll
    for (int off = 32; off; off >>= 1) s = __fadd_rn(s, __shfl_xor(s, off));
    if (l == 0) { rowmax[r] = m; rowsum[r] = s; }
}

// ---------- Kernel B: one wave per class — gather valid, sort, NMS, append kept + hist ----------

__global__ __launch_bounds__(64) void k_nms_class(const float* __restrict__ logits,
                                                  const float* __restrict__ reg,
                                                  const float* __restrict__ prop,
                                                  const float* __restrict__ rowmax,
                                                  const float* __restrict__ rowsum,
                                                  const int* __restrict__ piw,
                                                  const int* __restrict__ pih,
                                                  float* __restrict__ kscores,
                                                  int* __restrict__ kflats,
                                                  int* __restrict__ gcount,
                                                  int* __restrict__ hist,
                                                  int cap) {
    __shared__ float us[MAXC];    __shared__ int uidx[MAXC];
    __shared__ float ss[MAXC];    __shared__ int sidx[MAXC];
    __shared__ float bx[MAXC][4];
    __shared__ int   supp[MAXC];
    __shared__ int   cnt;

    const int cidx = blockIdx.x;       // 0..79
    const int ccol = cidx + 1;         // skip background class 0
    const int t = threadIdx.x;

    if (t == 0) cnt = 0;
    __syncthreads();

    // 1) valid candidates (score > thresh), unsorted compaction into LDS
    for (int r = t; r < R_ROWS; r += 64) {
        float z = logits[r * NCLS + ccol];
        float s = expf(__fsub_rn(z, rowmax[r])) / rowsum[r];
        if (s > SCORE_T) {
            int p = atomicAdd(&cnt, 1);
            us[p] = s; uidx[p] = r;
        }
    }
    __syncthreads();
    const int M = cnt;

    // 2) exact rank sort: (score desc, row asc) — matches stable argsort(-masked)
    for (int i = t; i < M; i += 64) {
        float si = us[i]; int ri = uidx[i];
        int rank = 0;
        for (int j = 0; j < M; j++) {
            float sj = us[j]; int rj = uidx[j];
            rank += (sj > si) || (sj == si && rj < ri);
        }
        ss[rank] = si; sidx[rank] = ri;
    }
    __syncthreads();

    // 3) decode + clip boxes for sorted candidates
    const float wmax = (float)(*piw - 1);
    const float hmax = (float)(*pih - 1);
    for (int i = t; i < M; i += 64) {
        float4 b = decode_clip(prop, reg, sidx[i], ccol, wmax, hmax);
        bx[i][0] = b.x; bx[i][1] = b.y; bx[i][2] = b.z; bx[i][3] = b.w;
        supp[i] = 0;
    }
    __syncthreads();

    // 4) greedy NMS: sequential over i, parallel suppression of j > i
    for (int i = 0; i < M; i++) {
        if (!supp[i]) {
            float ax1 = bx[i][0], ay1 = bx[i][1], ax2 = bx[i][2], ay2 = bx[i][3];
            for (int j = i + 1 + t; j < M; j += 64) {
                if (!supp[j]) {
                    float v = iou_legacy(ax1, ay1, ax2, ay2,
                                         bx[j][0], bx[j][1], bx[j][2], bx[j][3]);
                    if (v > NMS_T) supp[j] = 1;
                }
            }
        }
        __syncthreads();
    }

    // 5) append kept candidates to global list + score histogram
    for (int i = t; i < M; i += 64) {
        if (!supp[i]) {
            int p = atomicAdd(gcount, 1);
            if (p < cap) {
                kscores[p] = ss[i];
                kflats[p]  = cidx * R_ROWS + sidx[i];
                atomicAdd(&hist[bin_of(ss[i])], 1);
            }
        }
    }
}

// ---------- Kernel C: single block — histogram cutoff, compact, exact rank, finalize ----------

__global__ __launch_bounds__(256) void k_select(const float* __restrict__ kscores,
                                                const int* __restrict__ kflats,
                                                const int* __restrict__ gcount,
                                                int cap,
                                                const int* __restrict__ hist,
                                                const float* __restrict__ reg,
                                                const float* __restrict__ prop,
                                                const int* __restrict__ piw,
                                                const int* __restrict__ pih,
                                                float* __restrict__ out) {
    __shared__ int cs[256];
    __shared__ unsigned long long ck[SEL_CAP + 4];
    __shared__ float sel_s[DETS]; __shared__ int sel_f[DETS];
    __shared__ int sh_cut, sh_mcnt;

    const int t = threadIdx.x;
    int K = *gcount; if (K > cap) K = cap;
    const int target = (K < DETS) ? K : DETS;   // = nsel

    // ---- suffix scan of 1024-bin histogram: S[b] = #entries with bin >= b ----
    int v0 = hist[4 * t], v1 = hist[4 * t + 1], v2 = hist[4 * t + 2], v3 = hist[4 * t + 3];
    int s3 = v3, s2 = v2 + s3, s1 = v1 + s2, s0 = v0 + s1;
    cs[t] = s0;
    __syncthreads();
    for (int off = 1; off < 256; off <<= 1) {
        int x = cs[t] + ((t + off < 256) ? cs[t + off] : 0);
        __syncthreads();
        cs[t] = x;
        __syncthreads();
    }
    int tail = (t < 255) ? cs[t + 1] : 0;
    int S0 = s0 + tail, S1 = s1 + tail, S2 = s2 + tail, S3 = s3 + tail;
    if (t == 0) { sh_cut = 0; sh_mcnt = 0; }
    __syncthreads();
    if (target > 0) {
        int best = -1;
        if      (S3 >= target) best = 4 * t + 3;
        else if (S2 >= target) best = 4 * t + 2;
        else if (S1 >= target) best = 4 * t + 1;
        else if (S0 >= target) best = 4 * t;
        if (best >= 0) atomicMax(&sh_cut, best);
    }
    __syncthreads();
    const int cut = sh_cut;   // all top-`target` keys have bin >= cut; S[cut] is small

    // ---- compact candidates with bin >= cut into LDS ----
    for (int i = t; i < K; i += 256) {
        float s = kscores[i];
        if (bin_of(s) >= cut) {
            int p = atomicAdd(&sh_mcnt, 1);
            if (p < SEL_CAP) ck[p] = key_of(s, (unsigned)kflats[i]);
        }
    }
    __syncthreads();
    const int Mc = sh_mcnt;

    if (Mc <= SEL_CAP) {
        // ---- exact rank among compacted (ranks == global ranks) ----
        int Mp = (Mc + 3) & ~3;
        if (t < Mp - Mc) ck[Mc + t] = 0;   // pad: key 0 never outranks a real key
        __syncthreads();
        for (int i = t; i < Mc; i += 256) {
            unsigned long long ki = ck[i];
            int r = 0;
            for (int j = 0; j < Mp; j += 4)
                r += (int)(ck[j] > ki) + (int)(ck[j + 1] > ki)
                   + (int)(ck[j + 2] > ki) + (int)(ck[j + 3] > ki);
            if (r < DETS) {
                sel_s[r] = __uint_as_float((unsigned)(ki >> 32));
                sel_f[r] = (int)(~(unsigned)ki);
            }
        }
    } else {
        // ---- safe fallback (degenerate tie flood): exact rank vs full global list ----
        for (int i = t; i < K; i += 256) {
            float s = kscores[i];
            if (bin_of(s) < cut) continue;
            unsigned long long ki = key_of(s, (unsigned)kflats[i]);
            int r = 0;
            for (int j = 0; j < K; j++)
                r += (int)(key_of(kscores[j], (unsigned)kflats[j]) > ki);
            if (r < DETS) {
                sel_s[r] = __uint_as_float((unsigned)(ki >> 32));
                sel_f[r] = (int)(~(unsigned)ki);
            }
        }
    }
    __syncthreads();

    // ---- tail-fill (only when K < 100): smallest flats not in kept set, score NEG ----
    if (t == 0 && target < DETS) {
        int n = target, f = 0;
        while (n < DETS) {
            bool used = false;
            for (int q = 0; q < K; q++) if (kflats[q] == f) { used = true; break; }
            if (!used) { sel_s[n] = NEG_S; sel_f[n] = f; n++; }
            f++;
        }
    }
    __syncthreads();

    // ---- decode + write 600 outputs ----
    const float wmax = (float)(*piw - 1);
    const float hmax = (float)(*pih - 1);
    if (t < DETS) {
        int f = sel_f[t];
        int cidx = f / R_ROWS;
        int r    = f % R_ROWS;
        float4 b = decode_clip(prop, reg, r, cidx + 1, wmax, hmax);
        out[t] = sel_s[t];
        out[DETS + 4 * t + 0] = b.x;
        out[DETS + 4 * t + 1] = b.y;
        out[DETS + 4 * t + 2] = b.z;
        out[DETS + 4 * t + 3] = b.w;
        out[DETS * 5 + t] = (float)(cidx + 1);
    }
}

// ---------- host launcher ----------

extern "C" void kernel_launch(void* const* d_in, const int* in_sizes, int n_in,
                              void* d_out, int out_size, void* d_ws, size_t ws_size,
                              hipStream_t stream) {
    (void)in_sizes; (void)n_in; (void)out_size;
    const float* logits = (const float*)d_in[0];
    const float* reg    = (const float*)d_in[1];
    const float* prop   = (const float*)d_in[2];
    const int*   piw    = (const int*)d_in[3];
    const int*   pih    = (const int*)d_in[4];
    float* out = (float*)d_out;

    // workspace layout (bytes):
    //   0      hist[1024]          (4096)
    //   4096   gcount              (4)
    //   4224   rowmax[1000]        (4000)
    //   8256   rowsum[1000]        (4000)
    //   12288  kscores[cap] ; kflats[cap]
    char* ws = (char*)d_ws;
    int*   hist    = (int*)(ws);
    int*   gcount  = (int*)(ws + 4096);
    float* rowmax  = (float*)(ws + 4224);
    float* rowsum  = (float*)(ws + 8256);
    char*  listbuf = ws + 12288;

    long avail = (long)ws_size - 12288;
    int cap = CAP_DEFAULT;
    if (avail < (long)cap * 8) cap = (int)(avail / 8);
    if (cap < 1) cap = 1;
    float* kscores = (float*)listbuf;
    int*   kflats  = (int*)(listbuf + (size_t)cap * 4);

    k_softmax_stats<<<dim3(R_ROWS), dim3(64), 0, stream>>>(logits, rowmax, rowsum, gcount, hist);
    k_nms_class<<<dim3(NCLS - 1), dim3(64), 0, stream>>>(logits, reg, prop, rowmax, rowsum,
                                                         piw, pih, kscores, kflats, gcount, hist, cap);
    k_select<<<dim3(1), dim3(256), 0, stream>>>(kscores, kflats, gcount, cap, hist,
                                                reg, prop, piw, pih, out);
}

// Round 4
// 41.757 us; speedup vs baseline: 6.7339x; 1.0731x over previous
//
#include <hip/hip_runtime.h>
#include <cmath>

#define R_ROWS 1000
#define NCLS   81
#define REGW   (NCLS * 4)
#define SCORE_T 0.05f
#define NMS_T   0.5f
#define NEG_S  -1e9f
#define DETS   100
#define CLIP_V 4.135166556742356f   // log(1000/16)
#define MAXC   1000

#define NBINS   1024
#define SEL_CAP 2048
#define CAP_DEFAULT 20000           // max possible kept: <=19 classes/row (sum p = 1) * 1000 rows
#define NBLK_CLS (NCLS - 1)         // 80 class blocks

// ---------- exact-order helpers (no FMA contraction: match numpy/XLA separate rounding) ----------

__device__ __forceinline__ float4 decode_clip(const float* __restrict__ prop,
                                              const float* __restrict__ reg,
                                              int r, int ccol, float wmax, float hmax) {
    float x1 = prop[r * 4 + 0], y1 = prop[r * 4 + 1];
    float x2 = prop[r * 4 + 2], y2 = prop[r * 4 + 3];
    float w  = __fadd_rn(__fsub_rn(x2, x1), 1.0f);
    float h  = __fadd_rn(__fsub_rn(y2, y1), 1.0f);
    float cx = __fadd_rn(x1, __fmul_rn(0.5f, w));
    float cy = __fadd_rn(y1, __fmul_rn(0.5f, h));
    const float* rr = reg + r * REGW + 4 * ccol;
    float dx = rr[0] / 10.0f;
    float dy = rr[1] / 10.0f;
    float dw = fminf(rr[2] / 5.0f, CLIP_V);
    float dh = fminf(rr[3] / 5.0f, CLIP_V);
    float pcx = __fadd_rn(__fmul_rn(dx, w), cx);
    float pcy = __fadd_rn(__fmul_rn(dy, h), cy);
    float pw  = __fmul_rn(expf(dw), w);
    float ph  = __fmul_rn(expf(dh), h);
    float ox1 = __fsub_rn(pcx, __fmul_rn(0.5f, pw));
    float oy1 = __fsub_rn(pcy, __fmul_rn(0.5f, ph));
    float ox2 = __fsub_rn(__fadd_rn(pcx, __fmul_rn(0.5f, pw)), 1.0f);
    float oy2 = __fsub_rn(__fadd_rn(pcy, __fmul_rn(0.5f, ph)), 1.0f);
    float4 o;
    o.x = fminf(fmaxf(ox1, 0.0f), wmax);
    o.y = fminf(fmaxf(oy1, 0.0f), hmax);
    o.z = fminf(fmaxf(ox2, 0.0f), wmax);
    o.w = fminf(fmaxf(oy2, 0.0f), hmax);
    return o;
}

__device__ __forceinline__ float iou_legacy(float ax1, float ay1, float ax2, float ay2,
                                            float bx1, float by1, float bx2, float by2) {
    float aw = __fadd_rn(__fsub_rn(ax2, ax1), 1.0f);
    float ah = __fadd_rn(__fsub_rn(ay2, ay1), 1.0f);
    float areaA = __fmul_rn(aw, ah);
    float bw = __fadd_rn(__fsub_rn(bx2, bx1), 1.0f);
    float bh = __fadd_rn(__fsub_rn(by2, by1), 1.0f);
    float areaB = __fmul_rn(bw, bh);
    float ltx = fmaxf(ax1, bx1), lty = fmaxf(ay1, by1);
    float rbx = fminf(ax2, bx2), rby = fminf(ay2, by2);
    float wx = fmaxf(__fadd_rn(__fsub_rn(rbx, ltx), 1.0f), 0.0f);
    float wy = fmaxf(__fadd_rn(__fsub_rn(rby, lty), 1.0f), 0.0f);
    float inter = __fmul_rn(wx, wy);
    float denom = __fsub_rn(__fadd_rn(areaA, areaB), inter);
    return inter / denom;
}

// monotone coarse bin of a positive float score (positive IEEE bits are order-preserving)
__device__ __forceinline__ int bin_of(float s) {
    int idx = (int)(__float_as_uint(s) >> 16) - 0x3D00;   // scores in (0.05,1] -> [76,640]
    return idx < 0 ? 0 : (idx > NBINS - 1 ? NBINS - 1 : idx);
}

__device__ __forceinline__ unsigned long long key_of(float s, unsigned f) {
    // (score desc, flat asc) as one monotone u64
    return ((unsigned long long)__float_as_uint(s) << 32) | (unsigned long long)(~f);
}

// ---------- Kernel A: per-row softmax stats + zero hist/gcount/done ----------

__global__ __launch_bounds__(64) void k_softmax_stats(const float* __restrict__ logits,
                                                      float* __restrict__ rowmax,
                                                      float* __restrict__ rowsum,
                                                      int* __restrict__ gcount,
                                                      int* __restrict__ done,
                                                      int* __restrict__ hist) {
    int r = blockIdx.x;
    int l = threadIdx.x;
    if (r < NBINS / 64) hist[r * 64 + l] = 0;
    if (r == 0 && l == 0) { *gcount = 0; *done = 0; }
    float v1 = logits[r * NCLS + l];
    float v2 = (l < NCLS - 64) ? logits[r * NCLS + 64 + l] : -INFINITY;
    float m = fmaxf(v1, v2);
    #pragma unroll
    for (int off = 32; off; off >>= 1) m = fmaxf(m, __shfl_xor(m, off));
    float s = expf(__fsub_rn(v1, m));
    if (l < NCLS - 64) s = __fadd_rn(s, expf(__fsub_rn(v2, m)));
    #pragma unroll
    for (int off = 32; off; off >>= 1) s = __fadd_rn(s, __shfl_xor(s, off));
    if (l == 0) { rowmax[r] = m; rowsum[r] = s; }
}

// ---------- Kernel B (fused): per-class NMS; last finishing block runs selection ----------

__global__ __launch_bounds__(256) void k_nms_select(const float* __restrict__ logits,
                                                    const float* __restrict__ reg,
                                                    const float* __restrict__ prop,
                                                    const float* __restrict__ rowmax,
                                                    const float* __restrict__ rowsum,
                                                    const int* __restrict__ piw,
                                                    const int* __restrict__ pih,
                                                    float* __restrict__ kscores,
                                                    int* __restrict__ kflats,
                                                    int* __restrict__ gcount,
                                                    int* __restrict__ done,
                                                    int* __restrict__ hist,
                                                    int cap,
                                                    float* __restrict__ out) {
    // ---- class-phase LDS ----
    __shared__ float us[MAXC];    __shared__ int uidx[MAXC];
    __shared__ float ss[MAXC];    __shared__ int sidx[MAXC];
    __shared__ float bx[MAXC][4];
    __shared__ int   supp[MAXC];
    __shared__ int   cnt;
    __shared__ int   sh_last;
    // ---- select-phase LDS ----
    __shared__ int cs[256];
    __shared__ unsigned long long ck[SEL_CAP + 4];
    __shared__ float sel_s[DETS]; __shared__ int sel_f[DETS];
    __shared__ int sh_cut, sh_mcnt;

    const int cidx = blockIdx.x;       // 0..79
    const int ccol = cidx + 1;         // skip background class 0
    const int t = threadIdx.x;
    const float wmax = (float)(*piw - 1);
    const float hmax = (float)(*pih - 1);

    if (t == 0) cnt = 0;
    __syncthreads();

    // 1) valid candidates (score > thresh), unsorted compaction into LDS
    for (int r = t; r < R_ROWS; r += 256) {
        float z = logits[r * NCLS + ccol];
        float s = expf(__fsub_rn(z, rowmax[r])) / rowsum[r];
        if (s > SCORE_T) {
            int p = atomicAdd(&cnt, 1);
            us[p] = s; uidx[p] = r;
        }
    }
    __syncthreads();
    const int M = cnt;

    // 2) exact rank sort: (score desc, row asc) — matches stable argsort(-masked)
    for (int i = t; i < M; i += 256) {
        float si = us[i]; int ri = uidx[i];
        int rank = 0;
        for (int j = 0; j < M; j++) {
            float sj = us[j]; int rj = uidx[j];
            rank += (sj > si) || (sj == si && rj < ri);
        }
        ss[rank] = si; sidx[rank] = ri;
    }
    __syncthreads();

    // 3) decode + clip boxes for sorted candidates
    for (int i = t; i < M; i += 256) {
        float4 b = decode_clip(prop, reg, sidx[i], ccol, wmax, hmax);
        bx[i][0] = b.x; bx[i][1] = b.y; bx[i][2] = b.z; bx[i][3] = b.w;
        supp[i] = 0;
    }
    __syncthreads();

    // 4) greedy NMS: sequential over i, parallel suppression of j > i
    for (int i = 0; i < M; i++) {
        if (!supp[i]) {
            float ax1 = bx[i][0], ay1 = bx[i][1], ax2 = bx[i][2], ay2 = bx[i][3];
            for (int j = i + 1 + t; j < M; j += 256) {
                if (!supp[j]) {
                    float v = iou_legacy(ax1, ay1, ax2, ay2,
                                         bx[j][0], bx[j][1], bx[j][2], bx[j][3]);
                    if (v > NMS_T) supp[j] = 1;
                }
            }
        }
        __syncthreads();
    }

    // 5) append kept candidates to global list + score histogram
    for (int i = t; i < M; i += 256) {
        if (!supp[i]) {
            int p = atomicAdd(gcount, 1);
            if (p < cap) {
                kscores[p] = ss[i];
                kflats[p]  = cidx * R_ROWS + sidx[i];
                atomicAdd(&hist[bin_of(ss[i])], 1);
            }
        }
    }

    // ---- last-block-done handoff ----
    __threadfence();                   // release: kscores/kflats visible device-wide
    __syncthreads();
    if (t == 0) sh_last = (atomicAdd(done, 1) == NBLK_CLS - 1) ? 1 : 0;
    __syncthreads();
    if (!sh_last) return;
    __threadfence();                   // acquire: see all other blocks' writes

    // ================= selection phase (runs in exactly one block) =================
    int K = *gcount; if (K > cap) K = cap;
    const int target = (K < DETS) ? K : DETS;   // = nsel

    // ---- suffix scan of 1024-bin histogram: S[b] = #entries with bin >= b ----
    int v0 = hist[4 * t], v1 = hist[4 * t + 1], v2 = hist[4 * t + 2], v3 = hist[4 * t + 3];
    int s3 = v3, s2 = v2 + s3, s1 = v1 + s2, s0 = v0 + s1;
    cs[t] = s0;
    __syncthreads();
    for (int off = 1; off < 256; off <<= 1) {
        int x = cs[t] + ((t + off < 256) ? cs[t + off] : 0);
        __syncthreads();
        cs[t] = x;
        __syncthreads();
    }
    int tail = (t < 255) ? cs[t + 1] : 0;
    int S0 = s0 + tail, S1 = s1 + tail, S2 = s2 + tail, S3 = s3 + tail;
    if (t == 0) { sh_cut = 0; sh_mcnt = 0; }
    __syncthreads();
    if (target > 0) {
        int best = -1;
        if      (S3 >= target) best = 4 * t + 3;
        else if (S2 >= target) best = 4 * t + 2;
        else if (S1 >= target) best = 4 * t + 1;
        else if (S0 >= target) best = 4 * t;
        if (best >= 0) atomicMax(&sh_cut, best);
    }
    __syncthreads();
    const int cut = sh_cut;   // all top-`target` keys have bin >= cut; S[cut] is small

    // ---- compact candidates with bin >= cut into LDS ----
    for (int i = t; i < K; i += 256) {
        float s = kscores[i];
        if (bin_of(s) >= cut) {
            int p = atomicAdd(&sh_mcnt, 1);
            if (p < SEL_CAP) ck[p] = key_of(s, (unsigned)kflats[i]);
        }
    }
    __syncthreads();
    const int Mc = sh_mcnt;

    if (Mc <= SEL_CAP) {
        // ---- exact rank among compacted (ranks == global ranks) ----
        int Mp = (Mc + 3) & ~3;
        if (t < Mp - Mc) ck[Mc + t] = 0;   // pad: key 0 never outranks a real key
        __syncthreads();
        for (int i = t; i < Mc; i += 256) {
            unsigned long long ki = ck[i];
            int r = 0;
            for (int j = 0; j < Mp; j += 4)
                r += (int)(ck[j] > ki) + (int)(ck[j + 1] > ki)
                   + (int)(ck[j + 2] > ki) + (int)(ck[j + 3] > ki);
            if (r < DETS) {
                sel_s[r] = __uint_as_float((unsigned)(ki >> 32));
                sel_f[r] = (int)(~(unsigned)ki);
            }
        }
    } else {
        // ---- safe fallback (degenerate tie flood): exact rank vs full global list ----
        for (int i = t; i < K; i += 256) {
            float s = kscores[i];
            if (bin_of(s) < cut) continue;
            unsigned long long ki = key_of(s, (unsigned)kflats[i]);
            int r = 0;
            for (int j = 0; j < K; j++)
                r += (int)(key_of(kscores[j], (unsigned)kflats[j]) > ki);
            if (r < DETS) {
                sel_s[r] = __uint_as_float((unsigned)(ki >> 32));
                sel_f[r] = (int)(~(unsigned)ki);
            }
        }
    }
    __syncthreads();

    // ---- tail-fill (only when K < 100): smallest flats not in kept set, score NEG ----
    if (t == 0 && target < DETS) {
        int n = target, f = 0;
        while (n < DETS) {
            bool used = false;
            for (int q = 0; q < K; q++) if (kflats[q] == f) { used = true; break; }
            if (!used) { sel_s[n] = NEG_S; sel_f[n] = f; n++; }
            f++;
        }
    }
    __syncthreads();

    // ---- decode + write 600 outputs ----
    if (t < DETS) {
        int f = sel_f[t];
        int c2 = f / R_ROWS;
        int r  = f % R_ROWS;
        float4 b = decode_clip(prop, reg, r, c2 + 1, wmax, hmax);
        out[t] = sel_s[t];
        out[DETS + 4 * t + 0] = b.x;
        out[DETS + 4 * t + 1] = b.y;
        out[DETS + 4 * t + 2] = b.z;
        out[DETS + 4 * t + 3] = b.w;
        out[DETS * 5 + t] = (float)(c2 + 1);
    }
}

// ---------- host launcher ----------

extern "C" void kernel_launch(void* const* d_in, const int* in_sizes, int n_in,
                              void* d_out, int out_size, void* d_ws, size_t ws_size,
                              hipStream_t stream) {
    (void)in_sizes; (void)n_in; (void)out_size;
    const float* logits = (const float*)d_in[0];
    const float* reg    = (const float*)d_in[1];
    const float* prop   = (const float*)d_in[2];
    const int*   piw    = (const int*)d_in[3];
    const int*   pih    = (const int*)d_in[4];
    float* out = (float*)d_out;

    // workspace layout (bytes):
    //   0      hist[1024]          (4096)
    //   4096   gcount              (4)
    //   4160   done                (4)
    //   4224   rowmax[1000]        (4000)
    //   8256   rowsum[1000]        (4000)
    //   12288  kscores[cap] ; kflats[cap]
    char* ws = (char*)d_ws;
    int*   hist    = (int*)(ws);
    int*   gcount  = (int*)(ws + 4096);
    int*   done    = (int*)(ws + 4160);
    float* rowmax  = (float*)(ws + 4224);
    float* rowsum  = (float*)(ws + 8256);
    char*  listbuf = ws + 12288;

    long avail = (long)ws_size - 12288;
    int cap = CAP_DEFAULT;
    if (avail < (long)cap * 8) cap = (int)(avail / 8);
    if (cap < 1) cap = 1;
    float* kscores = (float*)listbuf;
    int*   kflats  = (int*)(listbuf + (size_t)cap * 4);

    k_softmax_stats<<<dim3(R_ROWS), dim3(64), 0, stream>>>(logits, rowmax, rowsum,
                                                           gcount, done, hist);
    k_nms_select<<<dim3(NBLK_CLS), dim3(256), 0, stream>>>(logits, reg, prop, rowmax, rowsum,
                                                           piw, pih, kscores, kflats,
                                                           gcount, done, hist, cap, out);
}

// Round 5
// 37.253 us; speedup vs baseline: 7.5480x; 1.1209x over previous
//
#include <hip/hip_runtime.h>
#include <cmath>

#define R_ROWS 1000
#define NCLS   81
#define REGW   (NCLS * 4)
#define SCORE_T 0.05f
#define NMS_T   0.5f
#define NEG_S  -1e9f
#define DETS   100
#define CLIP_V 4.135166556742356f   // log(1000/16)
#define MAXC   1000

#define NBINS   1024
#define SEL_CAP 2048
#define CAP_DEFAULT 20000           // max possible kept: <=19 classes/row (sum p = 1) * 1000 rows
#define NBLK_CLS (NCLS - 1)         // 80 class blocks

// ---------- exact-order helpers (no FMA contraction: match numpy/XLA separate rounding) ----------

__device__ __forceinline__ float4 decode_clip(const float* __restrict__ prop,
                                              const float* __restrict__ reg,
                                              int r, int ccol, float wmax, float hmax) {
    float x1 = prop[r * 4 + 0], y1 = prop[r * 4 + 1];
    float x2 = prop[r * 4 + 2], y2 = prop[r * 4 + 3];
    float w  = __fadd_rn(__fsub_rn(x2, x1), 1.0f);
    float h  = __fadd_rn(__fsub_rn(y2, y1), 1.0f);
    float cx = __fadd_rn(x1, __fmul_rn(0.5f, w));
    float cy = __fadd_rn(y1, __fmul_rn(0.5f, h));
    const float* rr = reg + r * REGW + 4 * ccol;
    float dx = rr[0] / 10.0f;
    float dy = rr[1] / 10.0f;
    float dw = fminf(rr[2] / 5.0f, CLIP_V);
    float dh = fminf(rr[3] / 5.0f, CLIP_V);
    float pcx = __fadd_rn(__fmul_rn(dx, w), cx);
    float pcy = __fadd_rn(__fmul_rn(dy, h), cy);
    float pw  = __fmul_rn(expf(dw), w);
    float ph  = __fmul_rn(expf(dh), h);
    float ox1 = __fsub_rn(pcx, __fmul_rn(0.5f, pw));
    float oy1 = __fsub_rn(pcy, __fmul_rn(0.5f, ph));
    float ox2 = __fsub_rn(__fadd_rn(pcx, __fmul_rn(0.5f, pw)), 1.0f);
    float oy2 = __fsub_rn(__fadd_rn(pcy, __fmul_rn(0.5f, ph)), 1.0f);
    float4 o;
    o.x = fminf(fmaxf(ox1, 0.0f), wmax);
    o.y = fminf(fmaxf(oy1, 0.0f), hmax);
    o.z = fminf(fmaxf(ox2, 0.0f), wmax);
    o.w = fminf(fmaxf(oy2, 0.0f), hmax);
    return o;
}

__device__ __forceinline__ float iou_legacy(float ax1, float ay1, float ax2, float ay2,
                                            float bx1, float by1, float bx2, float by2) {
    float aw = __fadd_rn(__fsub_rn(ax2, ax1), 1.0f);
    float ah = __fadd_rn(__fsub_rn(ay2, ay1), 1.0f);
    float areaA = __fmul_rn(aw, ah);
    float bw = __fadd_rn(__fsub_rn(bx2, bx1), 1.0f);
    float bh = __fadd_rn(__fsub_rn(by2, by1), 1.0f);
    float areaB = __fmul_rn(bw, bh);
    float ltx = fmaxf(ax1, bx1), lty = fmaxf(ay1, by1);
    float rbx = fminf(ax2, bx2), rby = fminf(ay2, by2);
    float wx = fmaxf(__fadd_rn(__fsub_rn(rbx, ltx), 1.0f), 0.0f);
    float wy = fmaxf(__fadd_rn(__fsub_rn(rby, lty), 1.0f), 0.0f);
    float inter = __fmul_rn(wx, wy);
    float denom = __fsub_rn(__fadd_rn(areaA, areaB), inter);
    return inter / denom;
}

// monotone coarse bin of a positive float score (positive IEEE bits are order-preserving)
__device__ __forceinline__ int bin_of(float s) {
    int idx = (int)(__float_as_uint(s) >> 16) - 0x3D00;   // scores in (0.05,1] -> [76,640]
    return idx < 0 ? 0 : (idx > NBINS - 1 ? NBINS - 1 : idx);
}

__device__ __forceinline__ unsigned long long key_of(float s, unsigned f) {
    // (score desc, flat asc) as one monotone u64
    return ((unsigned long long)__float_as_uint(s) << 32) | (unsigned long long)(~f);
}

__device__ __forceinline__ float key_score(unsigned long long k) {
    return __uint_as_float((unsigned)(k >> 32));
}
__device__ __forceinline__ int key_flat(unsigned long long k) {
    return (int)(~(unsigned)k);
}

// device-scope (sc1) coherent access — per-access coherence, no L2 flush/inv fences
__device__ __forceinline__ void dev_store_u64(unsigned long long* p, unsigned long long v) {
    __hip_atomic_store(p, v, __ATOMIC_RELAXED, __HIP_MEMORY_SCOPE_AGENT);
}
__device__ __forceinline__ unsigned long long dev_load_u64(const unsigned long long* p) {
    return __hip_atomic_load(p, __ATOMIC_RELAXED, __HIP_MEMORY_SCOPE_AGENT);
}
__device__ __forceinline__ int dev_load_i32(const int* p) {
    return __hip_atomic_load(p, __ATOMIC_RELAXED, __HIP_MEMORY_SCOPE_AGENT);
}

// ---------- Kernel A: per-row softmax stats + zero hist/gcount/done ----------

__global__ __launch_bounds__(64) void k_softmax_stats(const float* __restrict__ logits,
                                                      float* __restrict__ rowmax,
                                                      float* __restrict__ rowsum,
                                                      int* __restrict__ gcount,
                                                      int* __restrict__ done,
                                                      int* __restrict__ hist) {
    int r = blockIdx.x;
    int l = threadIdx.x;
    if (r < NBINS / 64) hist[r * 64 + l] = 0;
    if (r == 0 && l == 0) { *gcount = 0; *done = 0; }
    float v1 = logits[r * NCLS + l];
    float v2 = (l < NCLS - 64) ? logits[r * NCLS + 64 + l] : -INFINITY;
    float m = fmaxf(v1, v2);
    #pragma unroll
    for (int off = 32; off; off >>= 1) m = fmaxf(m, __shfl_xor(m, off));
    float s = expf(__fsub_rn(v1, m));
    if (l < NCLS - 64) s = __fadd_rn(s, expf(__fsub_rn(v2, m)));
    #pragma unroll
    for (int off = 32; off; off >>= 1) s = __fadd_rn(s, __shfl_xor(s, off));
    if (l == 0) { rowmax[r] = m; rowsum[r] = s; }
}

// ---------- Kernel B (fused): per-class NMS; last finishing block runs selection ----------

__global__ __launch_bounds__(256) void k_nms_select(const float* __restrict__ logits,
                                                    const float* __restrict__ reg,
                                                    const float* __restrict__ prop,
                                                    const float* __restrict__ rowmax,
                                                    const float* __restrict__ rowsum,
                                                    const int* __restrict__ piw,
                                                    const int* __restrict__ pih,
                                                    unsigned long long* __restrict__ klist,
                                                    int* __restrict__ gcount,
                                                    int* __restrict__ done,
                                                    int* __restrict__ hist,
                                                    int cap,
                                                    float* __restrict__ out) {
    // ---- class-phase LDS ----
    __shared__ float us[MAXC];    __shared__ int uidx[MAXC];
    __shared__ float ss[MAXC];    __shared__ int sidx[MAXC];
    __shared__ float bx[MAXC][4];
    __shared__ int   supp[MAXC];
    __shared__ int   cnt;
    __shared__ int   sh_last;
    // ---- select-phase LDS ----
    __shared__ int cs[256];
    __shared__ unsigned long long ck[SEL_CAP + 4];
    __shared__ float sel_s[DETS]; __shared__ int sel_f[DETS];
    __shared__ int sh_cut, sh_mcnt;

    const int cidx = blockIdx.x;       // 0..79
    const int ccol = cidx + 1;         // skip background class 0
    const int t = threadIdx.x;
    const float wmax = (float)(*piw - 1);
    const float hmax = (float)(*pih - 1);

    if (t == 0) cnt = 0;
    __syncthreads();

    // 1) valid candidates (score > thresh), unsorted compaction into LDS
    for (int r = t; r < R_ROWS; r += 256) {
        float z = logits[r * NCLS + ccol];
        float s = expf(__fsub_rn(z, rowmax[r])) / rowsum[r];
        if (s > SCORE_T) {
            int p = atomicAdd(&cnt, 1);
            us[p] = s; uidx[p] = r;
        }
    }
    __syncthreads();
    const int M = cnt;

    // 2) exact rank sort: (score desc, row asc) — matches stable argsort(-masked)
    for (int i = t; i < M; i += 256) {
        float si = us[i]; int ri = uidx[i];
        int rank = 0;
        for (int j = 0; j < M; j++) {
            float sj = us[j]; int rj = uidx[j];
            rank += (sj > si) || (sj == si && rj < ri);
        }
        ss[rank] = si; sidx[rank] = ri;
    }
    __syncthreads();

    // 3) decode + clip boxes for sorted candidates
    for (int i = t; i < M; i += 256) {
        float4 b = decode_clip(prop, reg, sidx[i], ccol, wmax, hmax);
        bx[i][0] = b.x; bx[i][1] = b.y; bx[i][2] = b.z; bx[i][3] = b.w;
        supp[i] = 0;
    }
    __syncthreads();

    // 4) greedy NMS: sequential over i, parallel suppression of j > i
    for (int i = 0; i < M; i++) {
        if (!supp[i]) {
            float ax1 = bx[i][0], ay1 = bx[i][1], ax2 = bx[i][2], ay2 = bx[i][3];
            for (int j = i + 1 + t; j < M; j += 256) {
                if (!supp[j]) {
                    float v = iou_legacy(ax1, ay1, ax2, ay2,
                                         bx[j][0], bx[j][1], bx[j][2], bx[j][3]);
                    if (v > NMS_T) supp[j] = 1;
                }
            }
        }
        __syncthreads();
    }

    // 5) append kept candidates via device-coherent (sc1) stores — no cache fences needed
    for (int i = t; i < M; i += 256) {
        if (!supp[i]) {
            int p = atomicAdd(gcount, 1);   // device-scope by default
            if (p < cap) {
                dev_store_u64(&klist[p], key_of(ss[i], (unsigned)(cidx * R_ROWS + sidx[i])));
                atomicAdd(&hist[bin_of(ss[i])], 1);
            }
        }
    }

    // ---- last-block-done handoff ----
    // __syncthreads() drains vmcnt(0): all sc1 stores/atomics are at the coherence
    // point before the done increment. No __threadfence (avoids wbl2/inv L2 flushes).
    __syncthreads();
    if (t == 0) sh_last = (atomicAdd(done, 1) == NBLK_CLS - 1) ? 1 : 0;
    __syncthreads();
    if (!sh_last) return;

    // ================= selection phase (runs in exactly one block) =================
    int K = dev_load_i32(gcount); if (K > cap) K = cap;
    const int target = (K < DETS) ? K : DETS;   // = nsel

    // ---- suffix scan of 1024-bin histogram: S[b] = #entries with bin >= b ----
    int v0 = dev_load_i32(&hist[4 * t]);
    int v1 = dev_load_i32(&hist[4 * t + 1]);
    int v2 = dev_load_i32(&hist[4 * t + 2]);
    int v3 = dev_load_i32(&hist[4 * t + 3]);
    int s3 = v3, s2 = v2 + s3, s1 = v1 + s2, s0 = v0 + s1;
    cs[t] = s0;
    __syncthreads();
    for (int off = 1; off < 256; off <<= 1) {
        int x = cs[t] + ((t + off < 256) ? cs[t + off] : 0);
        __syncthreads();
        cs[t] = x;
        __syncthreads();
    }
    int tail = (t < 255) ? cs[t + 1] : 0;
    int S0 = s0 + tail, S1 = s1 + tail, S2 = s2 + tail, S3 = s3 + tail;
    if (t == 0) { sh_cut = 0; sh_mcnt = 0; }
    __syncthreads();
    if (target > 0) {
        int best = -1;
        if      (S3 >= target) best = 4 * t + 3;
        else if (S2 >= target) best = 4 * t + 2;
        else if (S1 >= target) best = 4 * t + 1;
        else if (S0 >= target) best = 4 * t;
        if (best >= 0) atomicMax(&sh_cut, best);
    }
    __syncthreads();
    const int cut = sh_cut;   // all top-`target` keys have bin >= cut; S[cut] is small

    // ---- compact candidates with bin >= cut into LDS (one 8B coherent load each) ----
    for (int i = t; i < K; i += 256) {
        unsigned long long k = dev_load_u64(&klist[i]);
        if (bin_of(key_score(k)) >= cut) {
            int p = atomicAdd(&sh_mcnt, 1);
            if (p < SEL_CAP) ck[p] = k;
        }
    }
    __syncthreads();
    const int Mc = sh_mcnt;

    if (Mc <= SEL_CAP) {
        // ---- exact rank among compacted (ranks == global ranks) ----
        int Mp = (Mc + 3) & ~3;
        if (t < Mp - Mc) ck[Mc + t] = 0;   // pad: key 0 never outranks a real key
        __syncthreads();
        for (int i = t; i < Mc; i += 256) {
            unsigned long long ki = ck[i];
            int r = 0;
            for (int j = 0; j < Mp; j += 4)
                r += (int)(ck[j] > ki) + (int)(ck[j + 1] > ki)
                   + (int)(ck[j + 2] > ki) + (int)(ck[j + 3] > ki);
            if (r < DETS) {
                sel_s[r] = key_score(ki);
                sel_f[r] = key_flat(ki);
            }
        }
    } else {
        // ---- safe fallback (degenerate tie flood): exact rank vs full global list ----
        for (int i = t; i < K; i += 256) {
            unsigned long long ki = dev_load_u64(&klist[i]);
            if (bin_of(key_score(ki)) < cut) continue;
            int r = 0;
            for (int j = 0; j < K; j++)
                r += (int)(dev_load_u64(&klist[j]) > ki);
            if (r < DETS) {
                sel_s[r] = key_score(ki);
                sel_f[r] = key_flat(ki);
            }
        }
    }
    __syncthreads();

    // ---- tail-fill (only when K < 100): smallest flats not in kept set, score NEG ----
    if (t == 0 && target < DETS) {
        int n = target, f = 0;
        while (n < DETS) {
            bool used = false;
            for (int q = 0; q < K; q++) if (key_flat(dev_load_u64(&klist[q])) == f) { used = true; break; }
            if (!used) { sel_s[n] = NEG_S; sel_f[n] = f; n++; }
            f++;
        }
    }
    __syncthreads();

    // ---- decode + write 600 outputs ----
    if (t < DETS) {
        int f = sel_f[t];
        int c2 = f / R_ROWS;
        int r  = f % R_ROWS;
        float4 b = decode_clip(prop, reg, r, c2 + 1, wmax, hmax);
        out[t] = sel_s[t];
        out[DETS + 4 * t + 0] = b.x;
        out[DETS + 4 * t + 1] = b.y;
        out[DETS + 4 * t + 2] = b.z;
        out[DETS + 4 * t + 3] = b.w;
        out[DETS * 5 + t] = (float)(c2 + 1);
    }
}

// ---------- host launcher ----------

extern "C" void kernel_launch(void* const* d_in, const int* in_sizes, int n_in,
                              void* d_out, int out_size, void* d_ws, size_t ws_size,
                              hipStream_t stream) {
    (void)in_sizes; (void)n_in; (void)out_size;
    const float* logits = (const float*)d_in[0];
    const float* reg    = (const float*)d_in[1];
    const float* prop   = (const float*)d_in[2];
    const int*   piw    = (const int*)d_in[3];
    const int*   pih    = (const int*)d_in[4];
    float* out = (float*)d_out;

    // workspace layout (bytes):
    //   0      hist[1024]          (4096)
    //   4096   gcount              (4)
    //   4160   done                (4)
    //   4224   rowmax[1000]        (4000)
    //   8256   rowsum[1000]        (4000)
    //   12288  klist[cap]          (8B each)
    char* ws = (char*)d_ws;
    int*   hist    = (int*)(ws);
    int*   gcount  = (int*)(ws + 4096);
    int*   done    = (int*)(ws + 4160);
    float* rowmax  = (float*)(ws + 4224);
    float* rowsum  = (float*)(ws + 8256);
    unsigned long long* klist = (unsigned long long*)(ws + 12288);

    long avail = (long)ws_size - 12288;
    int cap = CAP_DEFAULT;
    if (avail < (long)cap * 8) cap = (int)(avail / 8);
    if (cap < 1) cap = 1;

    k_softmax_stats<<<dim3(R_ROWS), dim3(64), 0, stream>>>(logits, rowmax, rowsum,
                                                           gcount, done, hist);
    k_nms_select<<<dim3(NBLK_CLS), dim3(256), 0, stream>>>(logits, reg, prop, rowmax, rowsum,
                                                           piw, pih, klist,
                                                           gcount, done, hist, cap, out);
}